// Round 1
// baseline (1022.984 us; speedup 1.0000x reference)
//
#include <hip/hip_runtime.h>

#define NROWS 4096
#define NCLASS 50257
#define BLK 256

__global__ void zero_out_kernel(float* out) { out[0] = 0.0f; }

__global__ __launch_bounds__(BLK) void ce_loss_kernel(
    const float* __restrict__ pred,
    const int* __restrict__ target,
    float* __restrict__ out) {
    const int row = blockIdx.x;
    const float* __restrict__ p = pred + (size_t)row * NCLASS;
    const int tid = threadIdx.x;

    // Online softmax accumulation: running max m, running sum l = sum exp(x - m)
    float m = -3.4e38f;
    float l = 0.0f;

    const int nvec = NCLASS / 4;           // 12564 float4s
    const float4* __restrict__ pv = (const float4*)p;
    for (int i = tid; i < nvec; i += BLK) {
        float4 v = pv[i];
        float vm = fmaxf(fmaxf(v.x, v.y), fmaxf(v.z, v.w));
        float nm = fmaxf(m, vm);
        l = l * __expf(m - nm)
          + __expf(v.x - nm) + __expf(v.y - nm)
          + __expf(v.z - nm) + __expf(v.w - nm);
        m = nm;
    }
    // tail (NCLASS % 4 == 1): element index nvec*4 .. NCLASS-1
    for (int j = nvec * 4 + tid; j < NCLASS; j += BLK) {
        float x = p[j];
        float nm = fmaxf(m, x);
        l = l * __expf(m - nm) + __expf(x - nm);
        m = nm;
    }

    // wave-level (64-lane) butterfly-style reduce of (m, l)
    #pragma unroll
    for (int off = 32; off > 0; off >>= 1) {
        float om = __shfl_down(m, off, 64);
        float ol = __shfl_down(l, off, 64);
        float nm = fmaxf(m, om);
        l = l * __expf(m - nm) + ol * __expf(om - nm);
        m = nm;
    }

    // cross-wave reduce via LDS (4 waves)
    __shared__ float sm[BLK / 64];
    __shared__ float sl[BLK / 64];
    const int wave = tid >> 6;
    const int lane = tid & 63;
    if (lane == 0) { sm[wave] = m; sl[wave] = l; }
    __syncthreads();

    if (tid == 0) {
        m = sm[0]; l = sl[0];
        #pragma unroll
        for (int w = 1; w < BLK / 64; ++w) {
            float om = sm[w], ol = sl[w];
            float nm = fmaxf(m, om);
            l = l * __expf(m - nm) + ol * __expf(om - nm);
            m = nm;
        }
        const int t = target[row];
        const float xt = p[t];                    // single gather, L2-warm
        const float logp = xt - m - __logf(l);    // log_softmax at target
        atomicAdd(out, -logp * (1.0f / (float)NROWS));
    }
}

extern "C" void kernel_launch(void* const* d_in, const int* in_sizes, int n_in,
                              void* d_out, int out_size, void* d_ws, size_t ws_size,
                              hipStream_t stream) {
    const float* pred = (const float*)d_in[0];
    const int* target = (const int*)d_in[1];
    float* out = (float*)d_out;

    // harness poisons d_out with 0xAA before every timed replay — zero it first
    zero_out_kernel<<<1, 1, 0, stream>>>(out);
    ce_loss_kernel<<<NROWS, BLK, 0, stream>>>(pred, target, out);
}

// Round 2
// 1017.532 us; speedup vs baseline: 1.0054x; 1.0054x over previous
//
#include <hip/hip_runtime.h>

#define NROWS 4096
#define NCLASS 50257
#define BLK 256

// Stage 1: one block per row, online-softmax, write per-row loss to workspace.
// No atomics — R0 showed 4096 same-address atomicAdds serialize to ~1 ms.
__global__ __launch_bounds__(BLK) void ce_row_kernel(
    const float* __restrict__ pred,
    const int* __restrict__ target,
    float* __restrict__ row_loss) {
    const int row = blockIdx.x;
    const float* __restrict__ p = pred + (size_t)row * NCLASS;
    const int tid = threadIdx.x;

    float m = -3.4e38f;
    float l = 0.0f;

    // Peel scalar head until 16B-aligned (row stride 50257*4 B is only 4B-aligned).
    const int head = (int)(((16u - (unsigned)((size_t)p & 15u)) & 15u) >> 2);
    if (tid < head) {
        m = p[tid];
        l = 1.0f;
    }

    const float4* __restrict__ pv = (const float4*)(p + head);
    const int nvec = (NCLASS - head) >> 2;
    for (int i = tid; i < nvec; i += BLK) {
        float4 v = pv[i];
        float vm = fmaxf(fmaxf(v.x, v.y), fmaxf(v.z, v.w));
        float nm = fmaxf(m, vm);
        l = l * __expf(m - nm)
          + __expf(v.x - nm) + __expf(v.y - nm)
          + __expf(v.z - nm) + __expf(v.w - nm);
        m = nm;
    }
    // scalar tail
    for (int j = head + (nvec << 2) + tid; j < NCLASS; j += BLK) {
        float x = p[j];
        float nm = fmaxf(m, x);
        l = l * __expf(m - nm) + __expf(x - nm);
        m = nm;
    }

    // wave-level reduce of (m, l)
    #pragma unroll
    for (int off = 32; off > 0; off >>= 1) {
        float om = __shfl_down(m, off, 64);
        float ol = __shfl_down(l, off, 64);
        float nm = fmaxf(m, om);
        l = l * __expf(m - nm) + ol * __expf(om - nm);
        m = nm;
    }

    // cross-wave reduce via LDS (4 waves)
    __shared__ float sm[BLK / 64];
    __shared__ float sl[BLK / 64];
    const int wave = tid >> 6;
    const int lane = tid & 63;
    if (lane == 0) { sm[wave] = m; sl[wave] = l; }
    __syncthreads();

    if (tid == 0) {
        m = sm[0]; l = sl[0];
        #pragma unroll
        for (int w = 1; w < BLK / 64; ++w) {
            float om = sm[w], ol = sl[w];
            float nm = fmaxf(m, om);
            l = l * __expf(m - nm) + ol * __expf(om - nm);
            m = nm;
        }
        const int t = target[row];
        row_loss[row] = -(p[t] - m - __logf(l));
    }
}

// Stage 2: single block sums the 4096 per-row losses, writes the scalar.
// Overwrites the 0xAA-poisoned d_out directly — no zero-init kernel needed.
__global__ __launch_bounds__(BLK) void ce_reduce_kernel(
    const float* __restrict__ row_loss,
    float* __restrict__ out) {
    const int tid = threadIdx.x;
    float s = 0.0f;
    for (int i = tid; i < NROWS; i += BLK) s += row_loss[i];

    #pragma unroll
    for (int off = 32; off > 0; off >>= 1) s += __shfl_down(s, off, 64);

    __shared__ float sw[BLK / 64];
    if ((tid & 63) == 0) sw[tid >> 6] = s;
    __syncthreads();

    if (tid == 0) {
        float t = 0.0f;
        #pragma unroll
        for (int w = 0; w < BLK / 64; ++w) t += sw[w];
        out[0] = t * (1.0f / (float)NROWS);
    }
}

extern "C" void kernel_launch(void* const* d_in, const int* in_sizes, int n_in,
                              void* d_out, int out_size, void* d_ws, size_t ws_size,
                              hipStream_t stream) {
    const float* pred = (const float*)d_in[0];
    const int* target = (const int*)d_in[1];
    float* out = (float*)d_out;
    float* row_loss = (float*)d_ws;   // 4096 floats = 16 KB scratch

    ce_row_kernel<<<NROWS, BLK, 0, stream>>>(pred, target, row_loss);
    ce_reduce_kernel<<<1, BLK, 0, stream>>>(row_loss, out);
}